// Round 5
// baseline (610.437 us; speedup 1.0000x reference)
//
#include <hip/hip_runtime.h>
#include <hip/hip_fp16.h>
#include <math.h>

// Problem constants
#define NB 16     // batch
#define SQ 40     // seq len
#define HIDN 256  // hidden = E = R
#define CC 1024   // C
#define NROW 262144 // R*C

#define AGENT __HIP_MEMORY_SCOPE_AGENT
#define SENT 0x7E7E7E7Eu   // f16 NaN pattern; real h (tanh*sig, |h|<1) can never produce it

__device__ __forceinline__ float sigf(float x){ return 1.0f/(1.0f+__expf(-x)); }

typedef _Float16 h2v __attribute__((ext_vector_type(2)));
typedef _Float16 f16x8 __attribute__((ext_vector_type(8)));
typedef float    f32x4 __attribute__((ext_vector_type(4)));

__device__ __forceinline__ float fd2(unsigned w, unsigned h, float acc){
  h2v a = __builtin_bit_cast(h2v, w);
  h2v b = __builtin_bit_cast(h2v, h);
#if __has_builtin(__builtin_amdgcn_fdot2)
  return __builtin_amdgcn_fdot2(a, b, acc, false);
#else
  return acc + (float)a.x*(float)b.x + (float)a.y*(float)b.y;
#endif
}

__device__ __forceinline__ unsigned pkh(float lo, float hi){
  return (unsigned)__half_as_ushort(__float2half_rn(lo))
       | ((unsigned)__half_as_ushort(__float2half_rn(hi)) << 16);
}

// ---------------- K-prep: fused  [blocks 0..79] x-gates  |  [blocks 80..591] w_hh f16 repack
// xgates: XG[t*16+b][row] = emb[idx[b][t]] . w_ih[row] + b_ih + b_hh
// whh3:   u32 flat (((half*32+q)*512+t)*4+c); pair=4q+c; row=(t>>7)*256+half*128+(t&127)
__global__ __launch_bounds__(256) void k_prep(
    const int* __restrict__ idx, const float* __restrict__ emb,
    const float* __restrict__ w_ih, const float* __restrict__ b_ih,
    const float* __restrict__ b_hh, float* __restrict__ XG,
    const float* __restrict__ w_hh, unsigned* __restrict__ W3)
{
  __shared__ float xs[8*256];
  int t = threadIdx.x;
  if (blockIdx.x >= 80) {
    int tid = (blockIdx.x - 80)*256 + t;   // 131072 total
    int c    = tid & 3;
    int tt   = (tid >> 2) & 511;
    int q    = (tid >> 11) & 31;
    int half = tid >> 16;
    int pair = 4*q + c;
    int g = tt >> 7, j = tt & 127;
    int row = g*256 + half*128 + j;
    float2 v = *(const float2*)&w_hh[(size_t)row*256 + 2*pair];
    W3[tid] = pkh(v.x, v.y);
    return;
  }
  int tb0 = blockIdx.x * 8;
  #pragma unroll
  for (int i = 0; i < 8; ++i) {
    int flat = t + i*256;
    int p = flat >> 8, k = flat & 255;
    int tb = tb0 + p;
    int ts = tb >> 4, b = tb & 15;
    int row = idx[b*SQ + ts];
    xs[p*256 + k] = emb[row*256 + k];
  }
  __syncthreads();
  int rows[4];
  float acc[4][8];
  #pragma unroll
  for (int r = 0; r < 4; ++r) {
    rows[r] = t + r*256;
    float bias = b_ih[rows[r]] + b_hh[rows[r]];
    #pragma unroll
    for (int p = 0; p < 8; ++p) acc[r][p] = bias;
  }
  for (int k16 = 0; k16 < 16; ++k16) {
    float4 w[4][4];
    #pragma unroll
    for (int r = 0; r < 4; ++r)
      #pragma unroll
      for (int q = 0; q < 4; ++q)
        w[r][q] = *(const float4*)&w_ih[rows[r]*256 + k16*16 + q*4];
    #pragma unroll
    for (int p = 0; p < 8; ++p) {
      #pragma unroll
      for (int q = 0; q < 4; ++q) {
        float4 x = *(const float4*)&xs[p*256 + k16*16 + q*4];
        #pragma unroll
        for (int r = 0; r < 4; ++r)
          acc[r][p] += w[r][q].x*x.x + w[r][q].y*x.y + w[r][q].z*x.z + w[r][q].w*x.w;
      }
    }
  }
  #pragma unroll
  for (int p = 0; p < 8; ++p)
    #pragma unroll
    for (int r = 0; r < 4; ++r)
      XG[(tb0 + p)*1024 + rows[r]] = acc[r][p];
}

// ---------------- K1: fused  [blocks 0..31] LSTM  |  [blocks 32..543] feature transpose->f16
// LSTM: 2 blocks/batch (b=bid&15, half=bid>>4 -> pair b,b+16 lands on same XCD under %8
// round-robin; correctness placement-independent). 512 thr; thread t owns gate row
// (t>>7)*256 + half*128 + (t&127); 256 w_hh weights in 128 packed-f16 VGPRs.
// featT: tiles of 64c x 256p; 2 sub-tiles (256 thr each) per block; coalesced read of
// feat[b][c][p] rows, LDS transpose, 128 B-contig f16 row writes to fT[b][p][c].
__global__ __launch_bounds__(512) void k_lstm_ft(
    const float* __restrict__ XG, const uint4* __restrict__ W3,
    const int* __restrict__ lens, const float* __restrict__ e2d_w,
    const float* __restrict__ e2d_b, float* __restrict__ instr,
    unsigned* __restrict__ hcomm,
    const float* __restrict__ feat, _Float16* __restrict__ fT)
{
  __shared__ __align__(16) char smem[73728];   // max(lstm 3.6 KB, featT 2x36 KB)

  int t = threadIdx.x;

  if (blockIdx.x >= 32) {
    // ---- feature transpose sub-kernel ----
    int sub = t >> 8, t2 = t & 255;
    int tile = (blockIdx.x - 32)*2 + sub;    // 0..1023 = 16 b x 16 ct x 4 pt
    int b  = tile >> 6;
    int rem = tile & 63;
    int c0 = (rem >> 2) * 64;
    int p0 = (rem & 3) * 256;
    _Float16* tl = (_Float16*)smem + (size_t)sub*(256*72);  // [256 p][72 c-halves]
    const float* src = feat + ((size_t)b*1024 + c0)*1024 + p0;
    int wv2 = t2 >> 6, l = t2 & 63;
    #pragma unroll
    for (int i = 0; i < 16; ++i) {
      int ci = i*4 + wv2;
      float4 v = *(const float4*)&src[(size_t)ci*1024 + 4*l];
      tl[(4*l + 0)*72 + ci] = (_Float16)v.x;
      tl[(4*l + 1)*72 + ci] = (_Float16)v.y;
      tl[(4*l + 2)*72 + ci] = (_Float16)v.z;
      tl[(4*l + 3)*72 + ci] = (_Float16)v.w;
    }
    __syncthreads();
    uint4* dst = (uint4*)&fT[((size_t)b*1024 + p0 + t2)*1024 + c0];
    #pragma unroll
    for (int j = 0; j < 8; ++j)
      dst[j] = *(const uint4*)&tl[t2*72 + j*8];
    return;
  }

  // ---- LSTM sub-kernel ----
  float* dot_s = (float*)smem;         // [512]
  float* h_s   = dot_s + 512;          // [128]
  float* h_e   = h_s + 128;            // [256]

  int b    = blockIdx.x & 15;
  int half = blockIdx.x >> 4;
  int len  = lens[b];
  int lane = t & 63;

  // coalesced register weight load: 32 x uint4, lane-interleaved layout
  unsigned wv[128];
  {
    const uint4* wp = W3 + (size_t)half*32*512 + t;
    #pragma unroll
    for (int q = 0; q < 32; ++q) {
      uint4 v = wp[(size_t)q*512];
      wv[4*q+0]=v.x; wv[4*q+1]=v.y; wv[4*q+2]=v.z; wv[4*q+3]=v.w;
    }
  }

  int g = t >> 7, j = t & 127;
  int row = g*256 + half*128 + j;
  float c_reg = 0.0f, h_reg = 0.0f;

  float xg_cur = XG[(0*NB + b)*1024 + row];

  for (int it = 0; it < SQ; ++it) {
    float xg_next = (it+1 < SQ) ? XG[((it+1)*NB + b)*1024 + row] : 0.0f;
    float acc = xg_cur;   // includes b_ih + b_hh
    if (it > 0) {
      unsigned own = pkh(h_s[2*lane], h_s[2*lane + 1]);
      int owni = (int)own;
      const unsigned* oslot = hcomm + ((it-1)*NB + b)*128 + (half ? 0 : 64);
      if (half == 0) {
        #pragma unroll
        for (int q = 0; q < 64; ++q)
          acc = fd2(wv[q], (unsigned)__builtin_amdgcn_readlane(owni, q), acc);
        unsigned oth;
        do { oth = __hip_atomic_load(oslot + lane, __ATOMIC_RELAXED, AGENT); }
        while (__any((int)(oth == SENT)));
        int othi = (int)oth;
        #pragma unroll
        for (int q = 0; q < 64; ++q)
          acc = fd2(wv[64+q], (unsigned)__builtin_amdgcn_readlane(othi, q), acc);
      } else {
        #pragma unroll
        for (int q = 0; q < 64; ++q)
          acc = fd2(wv[64+q], (unsigned)__builtin_amdgcn_readlane(owni, q), acc);
        unsigned oth;
        do { oth = __hip_atomic_load(oslot + lane, __ATOMIC_RELAXED, AGENT); }
        while (__any((int)(oth == SENT)));
        int othi = (int)oth;
        #pragma unroll
        for (int q = 0; q < 64; ++q)
          acc = fd2(wv[q], (unsigned)__builtin_amdgcn_readlane(othi, q), acc);
      }
    }
    dot_s[t] = acc;
    __syncthreads();
    if (t < 128) {
      float iv = sigf (dot_s[t]);
      float fv = sigf (dot_s[t + 128]);
      float gv = tanhf(dot_s[t + 256]);
      float ov = sigf (dot_s[t + 384]);
      float cn = fv*c_reg + iv*gv;
      float hn = ov*tanhf(cn);
      if (it < len) { c_reg = cn; h_reg = hn; }
      h_s[t] = h_reg;
    }
    __syncthreads();
    if (t < 64)
      __hip_atomic_store(hcomm + (it*NB + b)*128 + half*64 + t,
                         pkh(h_s[2*t], h_s[2*t+1]), __ATOMIC_RELAXED, AGENT);
    xg_cur = xg_next;
  }

  // e2d epilogue on the half==0 block of each batch
  if (half == 0) {
    const unsigned* slot = hcomm + ((SQ-1)*NB + b)*128;
    if (t < 64) {
      unsigned v0, v1;
      do {
        v0 = __hip_atomic_load(slot + t,      __ATOMIC_RELAXED, AGENT);
        v1 = __hip_atomic_load(slot + 64 + t, __ATOMIC_RELAXED, AGENT);
      } while (__any((int)(v0 == SENT)) || __any((int)(v1 == SENT)));
      h2v lo = __builtin_bit_cast(h2v, v0);
      h2v hi = __builtin_bit_cast(h2v, v1);
      h_e[2*t]       = (float)lo.x;  h_e[2*t + 1]       = (float)lo.y;
      h_e[128 + 2*t] = (float)hi.x;  h_e[128 + 2*t + 1] = (float)hi.y;
    }
    __syncthreads();
    if (t < 256) {
      float acc2 = e2d_b[t];
      const float4* wp2 = (const float4*)&e2d_w[t*256];
      #pragma unroll 8
      for (int k4 = 0; k4 < 64; ++k4) {
        float4 w = wp2[k4];
        float4 h4 = *(const float4*)&h_e[k4*4];
        acc2 += w.x*h4.x + w.y*h4.y + w.z*h4.z + w.w*h4.w;
      }
      instr[b*256 + t] = tanhf(acc2);
    }
  }
}

// ---------------- K2: lin1 -> f16 output, 1 row/thread, grid 1024 (4 blocks/CU for TLP)
__global__ __launch_bounds__(256) void k_lin1(
    const float* __restrict__ instr, const float* __restrict__ w,
    const float* __restrict__ bias, _Float16* __restrict__ f1h)
{
  __shared__ float is[4096];
  int t = threadIdx.x;
  #pragma unroll
  for (int i = 0; i < 16; ++i) is[t + i*256] = instr[t + i*256];
  __syncthreads();
  int r0 = blockIdx.x*256 + t;
  const float* w0 = &w[(size_t)r0*256];
  float acc0[16];
  float bz0 = bias[r0];
  #pragma unroll
  for (int i = 0; i < 16; ++i) acc0[i] = bz0;
  for (int k16 = 0; k16 < 16; ++k16) {
    float4 a[4];
    #pragma unroll
    for (int q = 0; q < 4; ++q)
      a[q] = *(const float4*)&w0[k16*16 + q*4];
    #pragma unroll
    for (int bi = 0; bi < 16; ++bi) {
      #pragma unroll
      for (int q = 0; q < 4; ++q) {
        float4 x = *(const float4*)&is[bi*256 + k16*16 + q*4];
        acc0[bi] += a[q].x*x.x + a[q].y*x.y + a[q].z*x.z + a[q].w*x.w;
      }
    }
  }
  #pragma unroll
  for (int bi = 0; bi < 16; ++bi) {
    float v0 = acc0[bi]; v0 = v0 > 0.0f ? v0 : 0.01f*v0;
    f1h[(size_t)bi*NROW + r0] = (_Float16)v0;
  }
}

// ---------------- K3: f16 MFMA einsum on pre-transposed fT + fused relu->BN->max_r->clip.
// Grid: 256 = {b = bid&15, ptile = bid>>4} -> all 16 sharers of f1h[b] on one XCD.
// Block tile: 256 r x 64 p, K=1024 in chunks of 64 (16 iters). All loads coalesced uint4.
// mfma_f32_16x16x32_f16: D[m=r][n=p]; C/D: col(n)=lane&15, row(m)=(lane>>4)*4+reg.
__global__ __launch_bounds__(256, 1) void k_einsum_fT(
    const uint4* __restrict__ f1h4, const _Float16* __restrict__ fT,
    const float* __restrict__ gamma, const float* __restrict__ beta,
    const float* __restrict__ mean, const float* __restrict__ var,
    float* __restrict__ out)
{
  __shared__ unsigned ALDS[256*40];  // [r][80 halves] (64 k + 16 pad) = 40 KB
  __shared__ unsigned BLDS[64*40];   // [p][80 halves]                 = 10 KB
  __shared__ float sc_s[256], sh_s[256];
  __shared__ float red[4][64];

  int t = threadIdx.x;
  int b  = blockIdx.x & 15;
  int P0 = (blockIdx.x >> 4) * 64;
  int wr = t >> 6, lane = t & 63;     // wave tile: 64 r x 64 p
  int col = lane & 15, quad = lane >> 4;

  // BN constants
  {
    float s = gamma[t] * rsqrtf(var[t] + 1e-5f);
    sc_s[t] = s;
    sh_s[t] = beta[t] - mean[t]*s;
  }

  f32x4 acc[4][4];
  #pragma unroll
  for (int mt = 0; mt < 4; ++mt)
    #pragma unroll
    for (int nt = 0; nt < 4; ++nt) acc[mt][nt] = (f32x4)0.0f;

  // staging roles: A row t (128 uint4); B: 4 threads per p-row, 2 uint4 each per chunk
  const uint4* arow = f1h4 + ((size_t)b*NROW + (size_t)t*1024)/8;
  int p_loc = t >> 2, sub = t & 3;
  const uint4* brow = (const uint4*)(fT + ((size_t)b*1024 + P0 + p_loc)*1024);

  // prefetch chunk 0
  uint4 apf[8], bpf[2];
  #pragma unroll
  for (int g2 = 0; g2 < 8; ++g2) apf[g2] = arow[g2];
  bpf[0] = brow[sub*2];
  bpf[1] = brow[sub*2 + 1];

  for (int kc = 0; kc < 16; ++kc) {
    __syncthreads();   // previous frag reads done; sc_s visible on first iter
    #pragma unroll
    for (int g2 = 0; g2 < 8; ++g2)
      *(uint4*)&ALDS[t*40 + g2*4] = apf[g2];
    *(uint4*)&BLDS[p_loc*40 + sub*8]     = bpf[0];
    *(uint4*)&BLDS[p_loc*40 + sub*8 + 4] = bpf[1];
    __syncthreads();
    // prefetch next chunk (overlaps MFMA below)
    if (kc + 1 < 16) {
      #pragma unroll
      for (int g2 = 0; g2 < 8; ++g2) apf[g2] = arow[(kc+1)*8 + g2];
      bpf[0] = brow[(kc+1)*8 + sub*2];
      bpf[1] = brow[(kc+1)*8 + sub*2 + 1];
    }
    // fragments + MFMA (two k=32 steps per chunk)
    f16x8 bf[2][4];
    #pragma unroll
    for (int s = 0; s < 2; ++s)
      #pragma unroll
      for (int nt = 0; nt < 4; ++nt) {
        uint4 raw = *(const uint4*)&BLDS[(nt*16 + col)*40 + s*16 + quad*4];
        bf[s][nt] = __builtin_bit_cast(f16x8, raw);
      }
    #pragma unroll
    for (int s = 0; s < 2; ++s)
      #pragma unroll
      for (int mt = 0; mt < 4; ++mt) {
        uint4 raw = *(const uint4*)&ALDS[(wr*64 + mt*16 + col)*40 + s*16 + quad*4];
        f16x8 af = __builtin_bit_cast(f16x8, raw);
        #pragma unroll
        for (int nt = 0; nt < 4; ++nt)
          acc[mt][nt] = __builtin_amdgcn_mfma_f32_16x16x32_f16(af, bf[s][nt], acc[mt][nt], 0, 0, 0);
      }
  }

  // epilogue: relu -> BN -> max over r -> clip -> store
  float pmax[4];
  #pragma unroll
  for (int nt = 0; nt < 4; ++nt) pmax[nt] = -3.4e38f;
  #pragma unroll
  for (int mt = 0; mt < 4; ++mt) {
    int rb = wr*64 + mt*16 + quad*4;
    f32x4 scv = *(const f32x4*)&sc_s[rb];
    f32x4 shv = *(const f32x4*)&sh_s[rb];
    #pragma unroll
    for (int nt = 0; nt < 4; ++nt) {
      f32x4 a = acc[mt][nt];
      #pragma unroll
      for (int reg = 0; reg < 4; ++reg) {
        float v = fmaxf(a[reg], 0.0f)*scv[reg] + shv[reg];
        pmax[nt] = fmaxf(pmax[nt], v);
      }
    }
  }
  #pragma unroll
  for (int nt = 0; nt < 4; ++nt) {
    float m = pmax[nt];
    m = fmaxf(m, __shfl_xor(m, 16));
    m = fmaxf(m, __shfl_xor(m, 32));
    if (lane < 16) red[wr][nt*16 + lane] = m;
  }
  __syncthreads();
  if (t < 64) {
    float v = fmaxf(fmaxf(red[0][t], red[1][t]), fmaxf(red[2][t], red[3][t]));
    out[b*1024 + P0 + t] = fminf(fmaxf(v, 0.0f), 1.0f);
  }
}

extern "C" void kernel_launch(void* const* d_in, const int* in_sizes, int n_in,
                              void* d_out, int out_size, void* d_ws, size_t ws_size,
                              hipStream_t stream)
{
  const float* feature = (const float*)d_in[0];
  // d_in[1] = depth (unused), d_in[4] = only_train_rele (unused)
  const int*   idx     = (const int*)d_in[2];
  const int*   lens    = (const int*)d_in[3];
  const float* emb     = (const float*)d_in[5];
  const float* w_ih    = (const float*)d_in[6];
  const float* w_hh    = (const float*)d_in[7];
  const float* b_ih    = (const float*)d_in[8];
  const float* b_hh    = (const float*)d_in[9];
  const float* e2d_w   = (const float*)d_in[10];
  const float* e2d_b   = (const float*)d_in[11];
  const float* lin1_w  = (const float*)d_in[12];
  const float* lin1_b  = (const float*)d_in[13];
  const float* gamma   = (const float*)d_in[14];
  const float* beta    = (const float*)d_in[15];
  const float* mean    = (const float*)d_in[16];
  const float* var     = (const float*)d_in[17];

  char* ws = (char*)d_ws;
  float*    XG     = (float*)(ws);                 // 640*1024*4   = 2,621,440 B
  float*    instr  = (float*)(ws + 2621440);       // 4096*4       = 16,384 B
  unsigned* W3     = (unsigned*)(ws + 2637824);    // 512 KB
  unsigned* hcomm  = (unsigned*)(ws + 3162112);    // 40*16*128*4  = 327,680 B
  _Float16* f1h    = (_Float16*)(ws + 3489792);    // 16*262144*2  = 8,388,608 B
  _Float16* fT     = (_Float16*)(ws + 11878400);   // 16*1024*1024*2 = 33,554,432 B (total ~45 MB)

  hipMemsetAsync(hcomm, 0x7E, 327680, stream);     // f16-NaN sentinel in every h slot
  k_prep   <<<592,  256, 0, stream>>>(idx, emb, w_ih, b_ih, b_hh, XG, w_hh, W3);
  k_lstm_ft<<<544,  512, 0, stream>>>(XG, (const uint4*)W3, lens, e2d_w, e2d_b, instr, hcomm,
                                      feature, fT);
  k_lin1   <<<1024, 256, 0, stream>>>(instr, lin1_w, lin1_b, f1h);
  k_einsum_fT<<<256, 256, 0, stream>>>((const uint4*)f1h, fT, gamma, beta, mean, var,
                                       (float*)d_out);
}